// Round 10
// baseline (328.538 us; speedup 1.0000x reference)
//
#include <hip/hip_runtime.h>

// VectorQuantizer: z (32,256,32,32) f32, embedding (1024,256) f32.
// N=32768 rows (n = b*1024 + h*32 + w), D=256, K=1024.
// Out (f32, concat): z_q_st [8388608] (B,C,H,W), vq_loss [1], idx [32768].
// z_flat[n][c] = z[b*262144 + c*1024 + (n & 1023)]
//
// v6 = v5 with the latency-bound finishK split:
//   finishK: merge + np-f32 bit-exact refine + idx writes only (fast).
//   outputK: 2048 blocks (64 rows x 64-channel quarter), emb rows staged to
//            LDS (stride-65 pad -> conflict-free), z/out fully coalesced.
// distK (MFMA 2-limb bf16, unchanged from passing r9), prepBK, enormK same.
// ws: [0] loss f64; [64) enorm[1024]; [4352) B_pack 1MB; [1052928) pm1;
//     [1184000) pm2; [1315072) pk; [1446144) idx_buf int[32768].

#define TAU 4.0e-4f

typedef __attribute__((ext_vector_type(8))) short short8b;   // 8 bf16
typedef __attribute__((ext_vector_type(4))) float f32x4;

__device__ __forceinline__ unsigned short f2bf_rne(float x) {
  unsigned int u = __float_as_uint(x);
  unsigned int r = u + 0x7fffu + ((u >> 16) & 1u);
  return (unsigned short)(r >> 16);
}
__device__ __forceinline__ float bf2f(unsigned short s) {
  return __uint_as_float(((unsigned int)s) << 16);
}

__device__ __forceinline__ float np_pairwise256_sq(const float* a) {
  float tot = 0.0f;
#pragma unroll
  for (int blk = 0; blk < 2; ++blk) {
    const float* p = a + blk * 128;
    float r[8];
#pragma unroll
    for (int j = 0; j < 8; ++j) r[j] = __fmul_rn(p[j], p[j]);
    for (int i = 8; i < 128; i += 8) {
#pragma unroll
      for (int j = 0; j < 8; ++j) r[j] = __fadd_rn(r[j], __fmul_rn(p[i + j], p[i + j]));
    }
    float res = __fadd_rn(__fadd_rn(__fadd_rn(r[0], r[1]), __fadd_rn(r[2], r[3])),
                          __fadd_rn(__fadd_rn(r[4], r[5]), __fadd_rn(r[6], r[7])));
    tot = (blk == 0) ? res : __fadd_rn(tot, res);
  }
  return tot;
}

__global__ void initK(double* loss_sum) { *loss_sum = 0.0; }

__global__ __launch_bounds__(256) void enormK(const float* __restrict__ emb,
                                              float* __restrict__ enorm) {
  const int k = blockIdx.x * 256 + threadIdx.x;
  enorm[k] = np_pairwise256_sq(emb + (size_t)k * 256);
}

// B_pack: slot ushort-index = ((C*16 + limb*8 + kb)*64 + lane)*8.
__global__ __launch_bounds__(256) void prepBK(const float* __restrict__ emb,
                                              unsigned short* __restrict__ bp) {
  const int C = blockIdx.x;  // 64 code-blocks of 16
  const int t = threadIdx.x;
  const int n = t & 15, kb = (t >> 4) & 7, limb = t >> 7;
  const float* er = emb + (size_t)(C * 16 + n) * 256 + kb * 32;
#pragma unroll
  for (int s = 0; s < 4; ++s) {
    unsigned int w[4];
#pragma unroll
    for (int p = 0; p < 4; ++p) {
      unsigned short v2[2];
#pragma unroll
      for (int q = 0; q < 2; ++q) {
        float x = er[s * 8 + p * 2 + q];
        unsigned short hi = f2bf_rne(x);
        v2[q] = (limb == 0) ? hi : f2bf_rne(x - bf2f(hi));
      }
      w[p] = (unsigned int)v2[0] | ((unsigned int)v2[1] << 16);
    }
    size_t idx = ((size_t)(C * 16 + limb * 8 + kb) * 64 + (n + 16 * s)) * 8;
    *(uint4*)(bp + idx) = make_uint4(w[0], w[1], w[2], w[3]);
  }
}

// MFMA distance pass: wave = 16 rows x 1024 codes, (min1,min2,idx) -> ws.
__global__ __launch_bounds__(256) void distK(const float* __restrict__ z,
                                             const unsigned short* __restrict__ bp,
                                             const float* __restrict__ enorm,
                                             float* __restrict__ pm1,
                                             float* __restrict__ pm2,
                                             int* __restrict__ pk) {
  const int tid = threadIdx.x;
  const int wid = tid >> 6, lane = tid & 63;
  const int R = blockIdx.x * 4 + wid;  // 2048 row-blocks of 16
  const int n0w = R * 16;
  const int b = n0w >> 10, hw0 = n0w & 1023;
  const int s = lane >> 4, m = lane & 15;
  const float* zb = z + (size_t)b * 262144 + hw0 + m;

  short8b az[8], al[8];
#pragma unroll
  for (int kb = 0; kb < 8; ++kb) {
    float f[8];
#pragma unroll
    for (int i = 0; i < 8; ++i)
      f[i] = zb[(size_t)(kb * 32 + s * 8 + i) * 1024];
#pragma unroll
    for (int i = 0; i < 8; ++i) {
      unsigned short hi = f2bf_rne(f[i]);
      az[kb][i] = (short)hi;
      al[kb][i] = (short)f2bf_rne(f[i] - bf2f(hi));
    }
  }

  float m1[4], m2[4];
  int k1i[4];
#pragma unroll
  for (int r = 0; r < 4; ++r) { m1[r] = 3.0e38f; m2[r] = 3.0e38f; k1i[r] = 0; }

  short8b be[8], bl[8];
#pragma unroll
  for (int kb = 0; kb < 8; ++kb)
    be[kb] = *(const short8b*)(bp + ((size_t)kb * 64 + lane) * 8);

  for (int nt = 0; nt < 64; ++nt) {
    f32x4 acc = {0.0f, 0.0f, 0.0f, 0.0f};
    float en = enorm[nt * 16 + m];
#pragma unroll
    for (int kb = 0; kb < 8; ++kb)
      acc = __builtin_amdgcn_mfma_f32_16x16x32_bf16(az[kb], be[kb], acc, 0, 0, 0);
#pragma unroll
    for (int kb = 0; kb < 8; ++kb)
      bl[kb] = *(const short8b*)(bp + ((size_t)(nt * 16 + 8 + kb) * 64 + lane) * 8);
#pragma unroll
    for (int kb = 0; kb < 8; ++kb)
      acc = __builtin_amdgcn_mfma_f32_16x16x32_bf16(al[kb], be[kb], acc, 0, 0, 0);
    if (nt < 63) {
#pragma unroll
      for (int kb = 0; kb < 8; ++kb)
        be[kb] = *(const short8b*)(bp + ((size_t)((nt + 1) * 16 + kb) * 64 + lane) * 8);
    }
#pragma unroll
    for (int kb = 0; kb < 8; ++kb)
      acc = __builtin_amdgcn_mfma_f32_16x16x32_bf16(az[kb], bl[kb], acc, 0, 0, 0);
    const int code = nt * 16 + m;
#pragma unroll
    for (int r = 0; r < 4; ++r) {
      float v = en - 2.0f * acc[r];
      if (v < m1[r]) { m2[r] = m1[r]; m1[r] = v; k1i[r] = code; }
      else if (v < m2[r]) { m2[r] = v; }
    }
  }

#pragma unroll
  for (int r = 0; r < 4; ++r) {
    float a1 = m1[r], a2 = m2[r];
    int ai = k1i[r];
#pragma unroll
    for (int mask = 1; mask < 16; mask <<= 1) {
      float b1 = __shfl_xor(a1, mask);
      float b2 = __shfl_xor(a2, mask);
      int bi = __shfl_xor(ai, mask);
      if (b1 < a1 || (b1 == a1 && bi < ai)) { a2 = fminf(a1, b2); a1 = b1; ai = bi; }
      else { a2 = fminf(a2, b1); }
    }
    if (m == 0) {
      int n = n0w + s * 4 + r;
      pm1[n] = a1;
      pm2[n] = a2;
      pk[n] = ai;
    }
  }
}

// Merge + np-f32 bit-exact refine; writes idx (f32 out region + int ws).
__global__ __launch_bounds__(256) void finishK(const float* __restrict__ z,
                                               const float* __restrict__ emb,
                                               const float* __restrict__ enorm,
                                               const float* __restrict__ pm1,
                                               const float* __restrict__ pm2,
                                               const int* __restrict__ pk,
                                               int* __restrict__ idx_buf,
                                               float* __restrict__ out) {
  __shared__ float zrow[256];
  __shared__ int sidx[64];
  __shared__ unsigned long long sflag;
  __shared__ float swv[4];
  __shared__ int swi[4];

  const int tid = threadIdx.x;
  const int n0 = blockIdx.x * 64;
  const int b = n0 >> 10;
  const int hw0 = n0 & 1023;

  if (tid == 0) sflag = 0ull;
  if (tid < 64) {  // same wave as init -> ordered
    int n = n0 + tid;
    float a1 = pm1[n], a2 = pm2[n];
    sidx[tid] = pk[n];
    if (a2 - a1 < TAU) atomicOr(&sflag, 1ull << tid);
  }
  __syncthreads();

  unsigned long long flags = sflag;  // uniform across block
  while (flags) {
    int r = __ffsll(flags) - 1;
    flags &= flags - 1;
    __syncthreads();
    zrow[tid] = z[(size_t)b * 262144 + (size_t)tid * 1024 + hw0 + r];
    __syncthreads();
    float a32 = np_pairwise256_sq(zrow);
    const float* er0 = emb + (size_t)(tid * 4 + 0) * 256;
    const float* er1 = emb + (size_t)(tid * 4 + 1) * 256;
    const float* er2 = emb + (size_t)(tid * 4 + 2) * 256;
    const float* er3 = emb + (size_t)(tid * 4 + 3) * 256;
    float b0 = 0.0f, b1 = 0.0f, b2 = 0.0f, b3 = 0.0f;
    for (int d = 0; d < 256; ++d) {  // BLAS-style sequential FMA chains
      float zv = zrow[d];
      b0 = __fmaf_rn(zv, er0[d], b0);
      b1 = __fmaf_rn(zv, er1[d], b1);
      b2 = __fmaf_rn(zv, er2[d], b2);
      b3 = __fmaf_rn(zv, er3[d], b3);
    }
    float bch[4] = {b0, b1, b2, b3};
    float best = 3.0e38f;
    int bi = 1 << 30;
#pragma unroll
    for (int j = 0; j < 4; ++j) {
      const int k = tid * 4 + j;  // ascending -> first-index wins
      float tb = __fmul_rn(2.0f, bch[j]);
      float d32 = __fadd_rn(__fsub_rn(a32, tb), enorm[k]);
      if (d32 < best) { best = d32; bi = k; }
    }
    for (int mask = 1; mask < 64; mask <<= 1) {
      float ov = __shfl_xor(best, mask);
      int oi = __shfl_xor(bi, mask);
      if (ov < best || (ov == best && oi < bi)) { best = ov; bi = oi; }
    }
    if ((tid & 63) == 0) { swv[tid >> 6] = best; swi[tid >> 6] = bi; }
    __syncthreads();
    if (tid == 0) {
      float bv = swv[0];
      int bix = swi[0];
      for (int q = 1; q < 4; ++q)
        if (swv[q] < bv || (swv[q] == bv && swi[q] < bix)) { bv = swv[q]; bix = swi[q]; }
      sidx[r] = bix;
    }
    __syncthreads();
  }

  if (tid < 64) {
    out[(size_t)8388609 + n0 + tid] = (float)sidx[tid];
    idx_buf[n0 + tid] = sidx[tid];
  }
}

// z_q gather + z_q_st write + loss. Block = 64 rows x 64-channel quarter.
__global__ __launch_bounds__(256) void outputK(const float* __restrict__ z,
                                               const float* __restrict__ emb,
                                               const int* __restrict__ idx_buf,
                                               float* __restrict__ out,
                                               double* __restrict__ loss_sum) {
  __shared__ float el[64 * 65];  // stride-65 pad: (m+c)%32 banks -> conflict-free
  __shared__ int sidx[64];
  __shared__ double sloss[4];

  const int tid = threadIdx.x;
  const int rg = blockIdx.x >> 2;
  const int q = blockIdx.x & 3;       // channel quarter
  const int n0 = rg * 64;
  const int b = n0 >> 10;
  const int hw0 = n0 & 1023;

  if (tid < 64) sidx[tid] = idx_buf[n0 + tid];
  __syncthreads();

  // stage emb rows: wave reads one row's 64 consecutive floats (coalesced)
#pragma unroll
  for (int rep = 0; rep < 16; ++rep) {
    int idx = rep * 256 + tid;
    int r = idx >> 6, i = idx & 63;
    el[r * 65 + i] = emb[(size_t)sidx[r] * 256 + q * 64 + i];
  }
  __syncthreads();

  const int m = tid & 63;
  const int cq = tid >> 6;
  const size_t zb = (size_t)b * 262144 + hw0 + m;
  double acc = 0.0;
#pragma unroll
  for (int it = 0; it < 16; ++it) {
    int cl = it * 4 + cq;             // local channel 0..63
    int c = q * 64 + cl;
    float zv = z[zb + (size_t)c * 1024];
    float zq = el[m * 65 + cl];
    float d = zq - zv;
    out[zb + (size_t)c * 1024] = zv + d;  // z + (z_q - z), f32
    acc += (double)(d * d);
  }
  for (int mask = 1; mask < 64; mask <<= 1) acc += __shfl_xor(acc, mask);
  if ((tid & 63) == 0) sloss[tid >> 6] = acc;
  __syncthreads();
  if (tid == 0)
    atomicAdd(loss_sum, sloss[0] + sloss[1] + sloss[2] + sloss[3]);
}

__global__ void finalK(const double* loss_sum, float* out) {
  double s = *loss_sum;
  out[8388608] = (float)(1.25 * s / 8388608.0);  // (1+beta)*mean, beta=0.25
}

extern "C" void kernel_launch(void* const* d_in, const int* in_sizes, int n_in,
                              void* d_out, int out_size, void* d_ws, size_t ws_size,
                              hipStream_t stream) {
  const float* z = (const float*)d_in[0];
  const float* emb = (const float*)d_in[1];
  float* out = (float*)d_out;
  char* ws = (char*)d_ws;
  double* loss_sum = (double*)ws;
  float* enorm = (float*)(ws + 64);
  unsigned short* bp = (unsigned short*)(ws + 4352);  // 1 MB B_pack
  float* pm1 = (float*)(ws + 1052928);
  float* pm2 = (float*)(ws + 1184000);
  int* pk = (int*)(ws + 1315072);
  int* idx_buf = (int*)(ws + 1446144);

  initK<<<1, 1, 0, stream>>>(loss_sum);
  enormK<<<4, 256, 0, stream>>>(emb, enorm);
  prepBK<<<64, 256, 0, stream>>>(emb, bp);
  distK<<<512, 256, 0, stream>>>(z, bp, enorm, pm1, pm2, pk);
  finishK<<<512, 256, 0, stream>>>(z, emb, enorm, pm1, pm2, pk, idx_buf, out);
  outputK<<<2048, 256, 0, stream>>>(z, emb, idx_buf, out, loss_sum);
  finalK<<<1, 1, 0, stream>>>(loss_sum, out);
}

// Round 11
// 281.968 us; speedup vs baseline: 1.1652x; 1.1652x over previous
//
#include <hip/hip_runtime.h>

// VectorQuantizer: z (32,256,32,32) f32, embedding (1024,256) f32.
// N=32768 rows (n = b*1024 + h*32 + w), D=256, K=1024.
// Out (f32, concat): z_q_st [8388608] (B,C,H,W), vq_loss [1], idx [32768].
// z_flat[n][c] = z[b*262144 + c*1024 + (n & 1023)]
//
// v7 = v6 with the refine restructured (it was 192us of uncoalesced loads):
//   finishK: flat merge, prelim idx writes, compact flagged rows to rlist.
//   refineK: grid-stride over rlist; np-f32 bit-exact re-derivation with
//            COALESCED eT reads (same ascending-d FMA chain -> bit-identical).
// distK (MFMA 2-limb bf16), prepBK, enormK, outputK unchanged from r9/r10.
// ws: [0] loss f64; [16) rcount; [64) enorm 4KB; [4352) bp 1MB;
//     [1052928) eT 1MB; [2101504) pm1; [2232576) pm2; [2363648) pk;
//     [2494720) idx_buf; [2625792) rlist.

#define TAU 4.0e-4f

typedef __attribute__((ext_vector_type(8))) short short8b;   // 8 bf16
typedef __attribute__((ext_vector_type(4))) float f32x4;

__device__ __forceinline__ unsigned short f2bf_rne(float x) {
  unsigned int u = __float_as_uint(x);
  unsigned int r = u + 0x7fffu + ((u >> 16) & 1u);
  return (unsigned short)(r >> 16);
}
__device__ __forceinline__ float bf2f(unsigned short s) {
  return __uint_as_float(((unsigned int)s) << 16);
}

__device__ __forceinline__ float np_pairwise256_sq(const float* a) {
  float tot = 0.0f;
#pragma unroll
  for (int blk = 0; blk < 2; ++blk) {
    const float* p = a + blk * 128;
    float r[8];
#pragma unroll
    for (int j = 0; j < 8; ++j) r[j] = __fmul_rn(p[j], p[j]);
    for (int i = 8; i < 128; i += 8) {
#pragma unroll
      for (int j = 0; j < 8; ++j) r[j] = __fadd_rn(r[j], __fmul_rn(p[i + j], p[i + j]));
    }
    float res = __fadd_rn(__fadd_rn(__fadd_rn(r[0], r[1]), __fadd_rn(r[2], r[3])),
                          __fadd_rn(__fadd_rn(r[4], r[5]), __fadd_rn(r[6], r[7])));
    tot = (blk == 0) ? res : __fadd_rn(tot, res);
  }
  return tot;
}

__global__ void initK(double* loss_sum, int* rcount) {
  *loss_sum = 0.0;
  *rcount = 0;
}

__global__ __launch_bounds__(256) void enormK(const float* __restrict__ emb,
                                              float* __restrict__ enorm) {
  const int k = blockIdx.x * 256 + threadIdx.x;
  enorm[k] = np_pairwise256_sq(emb + (size_t)k * 256);
}

// eT[d][k] = emb[k][d], 32x32 LDS-tiled transpose.
__global__ __launch_bounds__(256) void transK(const float* __restrict__ emb,
                                              float* __restrict__ eT) {
  __shared__ float t[32][33];
  const int k0 = blockIdx.x * 32, d0 = blockIdx.y * 32;
  const int lx = threadIdx.x & 31, ly = threadIdx.x >> 5;
#pragma unroll
  for (int r = 0; r < 4; ++r)
    t[ly + r * 8][lx] = emb[(size_t)(k0 + ly + r * 8) * 256 + d0 + lx];
  __syncthreads();
#pragma unroll
  for (int r = 0; r < 4; ++r)
    eT[(size_t)(d0 + ly + r * 8) * 1024 + k0 + lx] = t[lx][ly + r * 8];
}

// B_pack: slot ushort-index = ((C*16 + limb*8 + kb)*64 + lane)*8.
__global__ __launch_bounds__(256) void prepBK(const float* __restrict__ emb,
                                              unsigned short* __restrict__ bp) {
  const int C = blockIdx.x;  // 64 code-blocks of 16
  const int t = threadIdx.x;
  const int n = t & 15, kb = (t >> 4) & 7, limb = t >> 7;
  const float* er = emb + (size_t)(C * 16 + n) * 256 + kb * 32;
#pragma unroll
  for (int s = 0; s < 4; ++s) {
    unsigned int w[4];
#pragma unroll
    for (int p = 0; p < 4; ++p) {
      unsigned short v2[2];
#pragma unroll
      for (int q = 0; q < 2; ++q) {
        float x = er[s * 8 + p * 2 + q];
        unsigned short hi = f2bf_rne(x);
        v2[q] = (limb == 0) ? hi : f2bf_rne(x - bf2f(hi));
      }
      w[p] = (unsigned int)v2[0] | ((unsigned int)v2[1] << 16);
    }
    size_t idx = ((size_t)(C * 16 + limb * 8 + kb) * 64 + (n + 16 * s)) * 8;
    *(uint4*)(bp + idx) = make_uint4(w[0], w[1], w[2], w[3]);
  }
}

// MFMA distance pass: wave = 16 rows x 1024 codes, (min1,min2,idx) -> ws.
__global__ __launch_bounds__(256) void distK(const float* __restrict__ z,
                                             const unsigned short* __restrict__ bp,
                                             const float* __restrict__ enorm,
                                             float* __restrict__ pm1,
                                             float* __restrict__ pm2,
                                             int* __restrict__ pk) {
  const int tid = threadIdx.x;
  const int wid = tid >> 6, lane = tid & 63;
  const int R = blockIdx.x * 4 + wid;  // 2048 row-blocks of 16
  const int n0w = R * 16;
  const int b = n0w >> 10, hw0 = n0w & 1023;
  const int s = lane >> 4, m = lane & 15;
  const float* zb = z + (size_t)b * 262144 + hw0 + m;

  short8b az[8], al[8];
#pragma unroll
  for (int kb = 0; kb < 8; ++kb) {
    float f[8];
#pragma unroll
    for (int i = 0; i < 8; ++i)
      f[i] = zb[(size_t)(kb * 32 + s * 8 + i) * 1024];
#pragma unroll
    for (int i = 0; i < 8; ++i) {
      unsigned short hi = f2bf_rne(f[i]);
      az[kb][i] = (short)hi;
      al[kb][i] = (short)f2bf_rne(f[i] - bf2f(hi));
    }
  }

  float m1[4], m2[4];
  int k1i[4];
#pragma unroll
  for (int r = 0; r < 4; ++r) { m1[r] = 3.0e38f; m2[r] = 3.0e38f; k1i[r] = 0; }

  short8b be[8], bl[8];
#pragma unroll
  for (int kb = 0; kb < 8; ++kb)
    be[kb] = *(const short8b*)(bp + ((size_t)kb * 64 + lane) * 8);

  for (int nt = 0; nt < 64; ++nt) {
    f32x4 acc = {0.0f, 0.0f, 0.0f, 0.0f};
    float en = enorm[nt * 16 + m];
#pragma unroll
    for (int kb = 0; kb < 8; ++kb)
      acc = __builtin_amdgcn_mfma_f32_16x16x32_bf16(az[kb], be[kb], acc, 0, 0, 0);
#pragma unroll
    for (int kb = 0; kb < 8; ++kb)
      bl[kb] = *(const short8b*)(bp + ((size_t)(nt * 16 + 8 + kb) * 64 + lane) * 8);
#pragma unroll
    for (int kb = 0; kb < 8; ++kb)
      acc = __builtin_amdgcn_mfma_f32_16x16x32_bf16(al[kb], be[kb], acc, 0, 0, 0);
    if (nt < 63) {
#pragma unroll
      for (int kb = 0; kb < 8; ++kb)
        be[kb] = *(const short8b*)(bp + ((size_t)((nt + 1) * 16 + kb) * 64 + lane) * 8);
    }
#pragma unroll
    for (int kb = 0; kb < 8; ++kb)
      acc = __builtin_amdgcn_mfma_f32_16x16x32_bf16(az[kb], bl[kb], acc, 0, 0, 0);
    const int code = nt * 16 + m;
#pragma unroll
    for (int r = 0; r < 4; ++r) {
      float v = en - 2.0f * acc[r];
      if (v < m1[r]) { m2[r] = m1[r]; m1[r] = v; k1i[r] = code; }
      else if (v < m2[r]) { m2[r] = v; }
    }
  }

#pragma unroll
  for (int r = 0; r < 4; ++r) {
    float a1 = m1[r], a2 = m2[r];
    int ai = k1i[r];
#pragma unroll
    for (int mask = 1; mask < 16; mask <<= 1) {
      float b1 = __shfl_xor(a1, mask);
      float b2 = __shfl_xor(a2, mask);
      int bi = __shfl_xor(ai, mask);
      if (b1 < a1 || (b1 == a1 && bi < ai)) { a2 = fminf(a1, b2); a1 = b1; ai = bi; }
      else { a2 = fminf(a2, b1); }
    }
    if (m == 0) {
      int n = n0w + s * 4 + r;
      pm1[n] = a1;
      pm2[n] = a2;
      pk[n] = ai;
    }
  }
}

// Flat merge + prelim idx writes + compact flagged rows.
__global__ __launch_bounds__(256) void finishK(const float* __restrict__ pm1,
                                               const float* __restrict__ pm2,
                                               const int* __restrict__ pk,
                                               int* __restrict__ idx_buf,
                                               float* __restrict__ out,
                                               int* __restrict__ rlist,
                                               int* __restrict__ rcount) {
  const int n = blockIdx.x * 256 + threadIdx.x;  // 128 blocks
  float a1 = pm1[n], a2 = pm2[n];
  int ai = pk[n];
  idx_buf[n] = ai;
  out[(size_t)8388609 + n] = (float)ai;
  if (a2 - a1 < TAU) {
    int p = atomicAdd(rcount, 1);
    rlist[p] = n;
  }
}

// np-f32 bit-exact re-derivation for flagged rows, coalesced via eT.
// b_j chain: fma over ascending d — identical arithmetic to emb-row version.
__global__ __launch_bounds__(256) void refineK(const float* __restrict__ z,
                                               const float* __restrict__ eT,
                                               const float* __restrict__ enorm,
                                               const int* __restrict__ rlist,
                                               const int* __restrict__ rcount,
                                               int* __restrict__ idx_buf,
                                               float* __restrict__ out) {
  __shared__ float zrow[256];
  __shared__ float swv[4];
  __shared__ int swi[4];
  const int tid = threadIdx.x;
  const int cnt = *rcount;
  for (int it = blockIdx.x; it < cnt; it += gridDim.x) {
    const int n = rlist[it];
    const int b = n >> 10, hw = n & 1023;
    __syncthreads();  // protect zrow across iterations
    zrow[tid] = z[(size_t)b * 262144 + (size_t)tid * 1024 + hw];
    __syncthreads();
    float a32 = np_pairwise256_sq(zrow);
    float b0 = 0.0f, b1 = 0.0f, b2 = 0.0f, b3 = 0.0f;
    for (int d = 0; d < 256; ++d) {  // BLAS-style sequential FMA chains
      float zv = zrow[d];
      float4 ev = *(const float4*)(eT + (size_t)d * 1024 + tid * 4);  // codes 4t..4t+3
      b0 = __fmaf_rn(zv, ev.x, b0);
      b1 = __fmaf_rn(zv, ev.y, b1);
      b2 = __fmaf_rn(zv, ev.z, b2);
      b3 = __fmaf_rn(zv, ev.w, b3);
    }
    float bch[4] = {b0, b1, b2, b3};
    float best = 3.0e38f;
    int bi = 1 << 30;
#pragma unroll
    for (int j = 0; j < 4; ++j) {
      const int k = tid * 4 + j;  // ascending -> first-index wins
      float tb = __fmul_rn(2.0f, bch[j]);
      float d32 = __fadd_rn(__fsub_rn(a32, tb), enorm[k]);
      if (d32 < best) { best = d32; bi = k; }
    }
    for (int mask = 1; mask < 64; mask <<= 1) {
      float ov = __shfl_xor(best, mask);
      int oi = __shfl_xor(bi, mask);
      if (ov < best || (ov == best && oi < bi)) { best = ov; bi = oi; }
    }
    if ((tid & 63) == 0) { swv[tid >> 6] = best; swi[tid >> 6] = bi; }
    __syncthreads();
    if (tid == 0) {
      float bv = swv[0];
      int bix = swi[0];
      for (int q = 1; q < 4; ++q)
        if (swv[q] < bv || (swv[q] == bv && swi[q] < bix)) { bv = swv[q]; bix = swi[q]; }
      idx_buf[n] = bix;
      out[(size_t)8388609 + n] = (float)bix;
    }
    __syncthreads();
  }
}

// z_q gather + z_q_st write + loss. Block = 64 rows x 64-channel quarter.
__global__ __launch_bounds__(256) void outputK(const float* __restrict__ z,
                                               const float* __restrict__ emb,
                                               const int* __restrict__ idx_buf,
                                               float* __restrict__ out,
                                               double* __restrict__ loss_sum) {
  __shared__ float el[64 * 65];  // stride-65 pad -> conflict-free
  __shared__ int sidx[64];
  __shared__ double sloss[4];

  const int tid = threadIdx.x;
  const int rg = blockIdx.x >> 2;
  const int q = blockIdx.x & 3;       // channel quarter
  const int n0 = rg * 64;
  const int b = n0 >> 10;
  const int hw0 = n0 & 1023;

  if (tid < 64) sidx[tid] = idx_buf[n0 + tid];
  __syncthreads();

#pragma unroll
  for (int rep = 0; rep < 16; ++rep) {
    int idx = rep * 256 + tid;
    int r = idx >> 6, i = idx & 63;
    el[r * 65 + i] = emb[(size_t)sidx[r] * 256 + q * 64 + i];
  }
  __syncthreads();

  const int m = tid & 63;
  const int cq = tid >> 6;
  const size_t zb = (size_t)b * 262144 + hw0 + m;
  double acc = 0.0;
#pragma unroll
  for (int it = 0; it < 16; ++it) {
    int cl = it * 4 + cq;             // local channel 0..63
    int c = q * 64 + cl;
    float zv = z[zb + (size_t)c * 1024];
    float zq = el[m * 65 + cl];
    float d = zq - zv;
    out[zb + (size_t)c * 1024] = zv + d;  // z + (z_q - z), f32
    acc += (double)(d * d);
  }
  for (int mask = 1; mask < 64; mask <<= 1) acc += __shfl_xor(acc, mask);
  if ((tid & 63) == 0) sloss[tid >> 6] = acc;
  __syncthreads();
  if (tid == 0)
    atomicAdd(loss_sum, sloss[0] + sloss[1] + sloss[2] + sloss[3]);
}

__global__ void finalK(const double* loss_sum, float* out) {
  double s = *loss_sum;
  out[8388608] = (float)(1.25 * s / 8388608.0);  // (1+beta)*mean, beta=0.25
}

extern "C" void kernel_launch(void* const* d_in, const int* in_sizes, int n_in,
                              void* d_out, int out_size, void* d_ws, size_t ws_size,
                              hipStream_t stream) {
  const float* z = (const float*)d_in[0];
  const float* emb = (const float*)d_in[1];
  float* out = (float*)d_out;
  char* ws = (char*)d_ws;
  double* loss_sum = (double*)ws;
  int* rcount = (int*)(ws + 16);
  float* enorm = (float*)(ws + 64);
  unsigned short* bp = (unsigned short*)(ws + 4352);  // 1 MB
  float* eT = (float*)(ws + 1052928);                 // 1 MB
  float* pm1 = (float*)(ws + 2101504);
  float* pm2 = (float*)(ws + 2232576);
  int* pk = (int*)(ws + 2363648);
  int* idx_buf = (int*)(ws + 2494720);
  int* rlist = (int*)(ws + 2625792);

  initK<<<1, 1, 0, stream>>>(loss_sum, rcount);
  enormK<<<4, 256, 0, stream>>>(emb, enorm);
  transK<<<dim3(32, 8), 256, 0, stream>>>(emb, eT);
  prepBK<<<64, 256, 0, stream>>>(emb, bp);
  distK<<<512, 256, 0, stream>>>(z, bp, enorm, pm1, pm2, pk);
  finishK<<<128, 256, 0, stream>>>(pm1, pm2, pk, idx_buf, out, rlist, rcount);
  refineK<<<256, 256, 0, stream>>>(z, eT, enorm, rlist, rcount, idx_buf, out);
  outputK<<<2048, 256, 0, stream>>>(z, emb, idx_buf, out, loss_sum);
  finalK<<<1, 1, 0, stream>>>(loss_sum, out);
}

// Round 12
// 249.026 us; speedup vs baseline: 1.3193x; 1.1323x over previous
//
#include <hip/hip_runtime.h>

// VectorQuantizer: z (32,256,32,32) f32, embedding (1024,256) f32.
// N=32768 rows (n = b*1024 + h*32 + w), D=256, K=1024.
// Out (f32, concat): z_q_st [8388608] (B,C,H,W), vq_loss [1], idx [32768].
// z_flat[n][c] = z[b*262144 + c*1024 + (n & 1023)]
//
// v8 = v7 with refineK restructured (was a 133us serial-latency chain):
//   4 rows per block in parallel -> each eT float4 feeds 16 independent FMAs;
//   depth-4 explicit prefetch (static indices). Chain order per (row,code)
//   unchanged (ascending d, __fmaf_rn) -> bit-identical to proven refine.
// distK (MFMA 2-limb bf16), prepBK, enormK, transK, finishK, outputK same.
// ws: [0] loss f64; [16) rcount; [64) enorm 4KB; [4352) bp 1MB;
//     [1052928) eT 1MB; [2101504) pm1; [2232576) pm2; [2363648) pk;
//     [2494720) idx_buf; [2625792) rlist.

#define TAU 4.0e-4f

typedef __attribute__((ext_vector_type(8))) short short8b;   // 8 bf16
typedef __attribute__((ext_vector_type(4))) float f32x4;

__device__ __forceinline__ unsigned short f2bf_rne(float x) {
  unsigned int u = __float_as_uint(x);
  unsigned int r = u + 0x7fffu + ((u >> 16) & 1u);
  return (unsigned short)(r >> 16);
}
__device__ __forceinline__ float bf2f(unsigned short s) {
  return __uint_as_float(((unsigned int)s) << 16);
}

__device__ __forceinline__ float np_pairwise256_sq(const float* a) {
  float tot = 0.0f;
#pragma unroll
  for (int blk = 0; blk < 2; ++blk) {
    const float* p = a + blk * 128;
    float r[8];
#pragma unroll
    for (int j = 0; j < 8; ++j) r[j] = __fmul_rn(p[j], p[j]);
    for (int i = 8; i < 128; i += 8) {
#pragma unroll
      for (int j = 0; j < 8; ++j) r[j] = __fadd_rn(r[j], __fmul_rn(p[i + j], p[i + j]));
    }
    float res = __fadd_rn(__fadd_rn(__fadd_rn(r[0], r[1]), __fadd_rn(r[2], r[3])),
                          __fadd_rn(__fadd_rn(r[4], r[5]), __fadd_rn(r[6], r[7])));
    tot = (blk == 0) ? res : __fadd_rn(tot, res);
  }
  return tot;
}

__global__ void initK(double* loss_sum, int* rcount) {
  *loss_sum = 0.0;
  *rcount = 0;
}

__global__ __launch_bounds__(256) void enormK(const float* __restrict__ emb,
                                              float* __restrict__ enorm) {
  const int k = blockIdx.x * 256 + threadIdx.x;
  enorm[k] = np_pairwise256_sq(emb + (size_t)k * 256);
}

// eT[d][k] = emb[k][d], 32x32 LDS-tiled transpose.
__global__ __launch_bounds__(256) void transK(const float* __restrict__ emb,
                                              float* __restrict__ eT) {
  __shared__ float t[32][33];
  const int k0 = blockIdx.x * 32, d0 = blockIdx.y * 32;
  const int lx = threadIdx.x & 31, ly = threadIdx.x >> 5;
#pragma unroll
  for (int r = 0; r < 4; ++r)
    t[ly + r * 8][lx] = emb[(size_t)(k0 + ly + r * 8) * 256 + d0 + lx];
  __syncthreads();
#pragma unroll
  for (int r = 0; r < 4; ++r)
    eT[(size_t)(d0 + ly + r * 8) * 1024 + k0 + lx] = t[lx][ly + r * 8];
}

// B_pack: slot ushort-index = ((C*16 + limb*8 + kb)*64 + lane)*8.
__global__ __launch_bounds__(256) void prepBK(const float* __restrict__ emb,
                                              unsigned short* __restrict__ bp) {
  const int C = blockIdx.x;  // 64 code-blocks of 16
  const int t = threadIdx.x;
  const int n = t & 15, kb = (t >> 4) & 7, limb = t >> 7;
  const float* er = emb + (size_t)(C * 16 + n) * 256 + kb * 32;
#pragma unroll
  for (int s = 0; s < 4; ++s) {
    unsigned int w[4];
#pragma unroll
    for (int p = 0; p < 4; ++p) {
      unsigned short v2[2];
#pragma unroll
      for (int q = 0; q < 2; ++q) {
        float x = er[s * 8 + p * 2 + q];
        unsigned short hi = f2bf_rne(x);
        v2[q] = (limb == 0) ? hi : f2bf_rne(x - bf2f(hi));
      }
      w[p] = (unsigned int)v2[0] | ((unsigned int)v2[1] << 16);
    }
    size_t idx = ((size_t)(C * 16 + limb * 8 + kb) * 64 + (n + 16 * s)) * 8;
    *(uint4*)(bp + idx) = make_uint4(w[0], w[1], w[2], w[3]);
  }
}

// MFMA distance pass: wave = 16 rows x 1024 codes, (min1,min2,idx) -> ws.
__global__ __launch_bounds__(256) void distK(const float* __restrict__ z,
                                             const unsigned short* __restrict__ bp,
                                             const float* __restrict__ enorm,
                                             float* __restrict__ pm1,
                                             float* __restrict__ pm2,
                                             int* __restrict__ pk) {
  const int tid = threadIdx.x;
  const int wid = tid >> 6, lane = tid & 63;
  const int R = blockIdx.x * 4 + wid;  // 2048 row-blocks of 16
  const int n0w = R * 16;
  const int b = n0w >> 10, hw0 = n0w & 1023;
  const int s = lane >> 4, m = lane & 15;
  const float* zb = z + (size_t)b * 262144 + hw0 + m;

  short8b az[8], al[8];
#pragma unroll
  for (int kb = 0; kb < 8; ++kb) {
    float f[8];
#pragma unroll
    for (int i = 0; i < 8; ++i)
      f[i] = zb[(size_t)(kb * 32 + s * 8 + i) * 1024];
#pragma unroll
    for (int i = 0; i < 8; ++i) {
      unsigned short hi = f2bf_rne(f[i]);
      az[kb][i] = (short)hi;
      al[kb][i] = (short)f2bf_rne(f[i] - bf2f(hi));
    }
  }

  float m1[4], m2[4];
  int k1i[4];
#pragma unroll
  for (int r = 0; r < 4; ++r) { m1[r] = 3.0e38f; m2[r] = 3.0e38f; k1i[r] = 0; }

  short8b be[8], bl[8];
#pragma unroll
  for (int kb = 0; kb < 8; ++kb)
    be[kb] = *(const short8b*)(bp + ((size_t)kb * 64 + lane) * 8);

  for (int nt = 0; nt < 64; ++nt) {
    f32x4 acc = {0.0f, 0.0f, 0.0f, 0.0f};
    float en = enorm[nt * 16 + m];
#pragma unroll
    for (int kb = 0; kb < 8; ++kb)
      acc = __builtin_amdgcn_mfma_f32_16x16x32_bf16(az[kb], be[kb], acc, 0, 0, 0);
#pragma unroll
    for (int kb = 0; kb < 8; ++kb)
      bl[kb] = *(const short8b*)(bp + ((size_t)(nt * 16 + 8 + kb) * 64 + lane) * 8);
#pragma unroll
    for (int kb = 0; kb < 8; ++kb)
      acc = __builtin_amdgcn_mfma_f32_16x16x32_bf16(al[kb], be[kb], acc, 0, 0, 0);
    if (nt < 63) {
#pragma unroll
      for (int kb = 0; kb < 8; ++kb)
        be[kb] = *(const short8b*)(bp + ((size_t)((nt + 1) * 16 + kb) * 64 + lane) * 8);
    }
#pragma unroll
    for (int kb = 0; kb < 8; ++kb)
      acc = __builtin_amdgcn_mfma_f32_16x16x32_bf16(az[kb], bl[kb], acc, 0, 0, 0);
    const int code = nt * 16 + m;
#pragma unroll
    for (int r = 0; r < 4; ++r) {
      float v = en - 2.0f * acc[r];
      if (v < m1[r]) { m2[r] = m1[r]; m1[r] = v; k1i[r] = code; }
      else if (v < m2[r]) { m2[r] = v; }
    }
  }

#pragma unroll
  for (int r = 0; r < 4; ++r) {
    float a1 = m1[r], a2 = m2[r];
    int ai = k1i[r];
#pragma unroll
    for (int mask = 1; mask < 16; mask <<= 1) {
      float b1 = __shfl_xor(a1, mask);
      float b2 = __shfl_xor(a2, mask);
      int bi = __shfl_xor(ai, mask);
      if (b1 < a1 || (b1 == a1 && bi < ai)) { a2 = fminf(a1, b2); a1 = b1; ai = bi; }
      else { a2 = fminf(a2, b1); }
    }
    if (m == 0) {
      int n = n0w + s * 4 + r;
      pm1[n] = a1;
      pm2[n] = a2;
      pk[n] = ai;
    }
  }
}

// Flat merge + prelim idx writes + compact flagged rows.
__global__ __launch_bounds__(256) void finishK(const float* __restrict__ pm1,
                                               const float* __restrict__ pm2,
                                               const int* __restrict__ pk,
                                               int* __restrict__ idx_buf,
                                               float* __restrict__ out,
                                               int* __restrict__ rlist,
                                               int* __restrict__ rcount) {
  const int n = blockIdx.x * 256 + threadIdx.x;  // 128 blocks
  float a1 = pm1[n], a2 = pm2[n];
  int ai = pk[n];
  idx_buf[n] = ai;
  out[(size_t)8388609 + n] = (float)ai;
  if (a2 - a1 < TAU) {
    int p = atomicAdd(rcount, 1);
    rlist[p] = n;
  }
}

// np-f32 bit-exact re-derivation, 4 rows per block in parallel.
// Each eT float4 feeds 16 independent FMA chains; depth-4 static prefetch.
__global__ __launch_bounds__(256) void refineK(const float* __restrict__ z,
                                               const float* __restrict__ eT,
                                               const float* __restrict__ enorm,
                                               const int* __restrict__ rlist,
                                               const int* __restrict__ rcount,
                                               int* __restrict__ idx_buf,
                                               float* __restrict__ out) {
  __shared__ float zrow[4][256];
  __shared__ float swv[4][4];
  __shared__ int swi[4][4];
  const int tid = threadIdx.x;
  const int cnt = *rcount;
  for (int base = blockIdx.x * 4; base < cnt; base += gridDim.x * 4) {
    __syncthreads();  // protect zrow/swv across iterations
#pragma unroll
    for (int r = 0; r < 4; ++r) {
      int ii = base + r;
      int n = rlist[ii < cnt ? ii : base];  // inactive rows duplicate row base
      int bb = n >> 10, hw = n & 1023;
      zrow[r][tid] = z[(size_t)bb * 262144 + (size_t)tid * 1024 + hw];
    }
    __syncthreads();
    float a32[4];
#pragma unroll
    for (int r = 0; r < 4; ++r) a32[r] = np_pairwise256_sq(zrow[r]);

    float bch[4][4];  // [row][code j], all statically indexed
#pragma unroll
    for (int r = 0; r < 4; ++r)
#pragma unroll
      for (int j = 0; j < 4; ++j) bch[r][j] = 0.0f;

    float4 evbuf[4];
#pragma unroll
    for (int p = 0; p < 4; ++p)
      evbuf[p] = *(const float4*)(eT + (size_t)p * 1024 + tid * 4);

    for (int d = 0; d < 256; d += 4) {
#pragma unroll
      for (int p = 0; p < 4; ++p) {
        float4 ev = evbuf[p];
        int nd = d + 4 + p;
        if (nd < 256)
          evbuf[p] = *(const float4*)(eT + (size_t)nd * 1024 + tid * 4);
#pragma unroll
        for (int r = 0; r < 4; ++r) {
          float zv = zrow[r][d + p];
          bch[r][0] = __fmaf_rn(zv, ev.x, bch[r][0]);
          bch[r][1] = __fmaf_rn(zv, ev.y, bch[r][1]);
          bch[r][2] = __fmaf_rn(zv, ev.z, bch[r][2]);
          bch[r][3] = __fmaf_rn(zv, ev.w, bch[r][3]);
        }
      }
    }

#pragma unroll
    for (int r = 0; r < 4; ++r) {
      float best = 3.0e38f;
      int bi = 1 << 30;
#pragma unroll
      for (int j = 0; j < 4; ++j) {
        const int k = tid * 4 + j;  // ascending -> first-index wins
        float tb = __fmul_rn(2.0f, bch[r][j]);
        float d32 = __fadd_rn(__fsub_rn(a32[r], tb), enorm[k]);
        if (d32 < best) { best = d32; bi = k; }
      }
      for (int mask = 1; mask < 64; mask <<= 1) {
        float ov = __shfl_xor(best, mask);
        int oi = __shfl_xor(bi, mask);
        if (ov < best || (ov == best && oi < bi)) { best = ov; bi = oi; }
      }
      if ((tid & 63) == 0) { swv[r][tid >> 6] = best; swi[r][tid >> 6] = bi; }
    }
    __syncthreads();
    if (tid < 4) {  // thread r finalizes row base+r
      int ii = base + tid;
      if (ii < cnt) {
        float bv = swv[tid][0];
        int bix = swi[tid][0];
#pragma unroll
        for (int q = 1; q < 4; ++q)
          if (swv[tid][q] < bv || (swv[tid][q] == bv && swi[tid][q] < bix)) {
            bv = swv[tid][q]; bix = swi[tid][q];
          }
        int n = rlist[ii];
        idx_buf[n] = bix;
        out[(size_t)8388609 + n] = (float)bix;
      }
    }
  }
}

// z_q gather + z_q_st write + loss. Block = 64 rows x 64-channel quarter.
__global__ __launch_bounds__(256) void outputK(const float* __restrict__ z,
                                               const float* __restrict__ emb,
                                               const int* __restrict__ idx_buf,
                                               float* __restrict__ out,
                                               double* __restrict__ loss_sum) {
  __shared__ float el[64 * 65];  // stride-65 pad -> conflict-free
  __shared__ int sidx[64];
  __shared__ double sloss[4];

  const int tid = threadIdx.x;
  const int rg = blockIdx.x >> 2;
  const int q = blockIdx.x & 3;       // channel quarter
  const int n0 = rg * 64;
  const int b = n0 >> 10;
  const int hw0 = n0 & 1023;

  if (tid < 64) sidx[tid] = idx_buf[n0 + tid];
  __syncthreads();

#pragma unroll
  for (int rep = 0; rep < 16; ++rep) {
    int idx = rep * 256 + tid;
    int r = idx >> 6, i = idx & 63;
    el[r * 65 + i] = emb[(size_t)sidx[r] * 256 + q * 64 + i];
  }
  __syncthreads();

  const int m = tid & 63;
  const int cq = tid >> 6;
  const size_t zb = (size_t)b * 262144 + hw0 + m;
  double acc = 0.0;
#pragma unroll
  for (int it = 0; it < 16; ++it) {
    int cl = it * 4 + cq;             // local channel 0..63
    int c = q * 64 + cl;
    float zv = z[zb + (size_t)c * 1024];
    float zq = el[m * 65 + cl];
    float d = zq - zv;
    out[zb + (size_t)c * 1024] = zv + d;  // z + (z_q - z), f32
    acc += (double)(d * d);
  }
  for (int mask = 1; mask < 64; mask <<= 1) acc += __shfl_xor(acc, mask);
  if ((tid & 63) == 0) sloss[tid >> 6] = acc;
  __syncthreads();
  if (tid == 0)
    atomicAdd(loss_sum, sloss[0] + sloss[1] + sloss[2] + sloss[3]);
}

__global__ void finalK(const double* loss_sum, float* out) {
  double s = *loss_sum;
  out[8388608] = (float)(1.25 * s / 8388608.0);  // (1+beta)*mean, beta=0.25
}

extern "C" void kernel_launch(void* const* d_in, const int* in_sizes, int n_in,
                              void* d_out, int out_size, void* d_ws, size_t ws_size,
                              hipStream_t stream) {
  const float* z = (const float*)d_in[0];
  const float* emb = (const float*)d_in[1];
  float* out = (float*)d_out;
  char* ws = (char*)d_ws;
  double* loss_sum = (double*)ws;
  int* rcount = (int*)(ws + 16);
  float* enorm = (float*)(ws + 64);
  unsigned short* bp = (unsigned short*)(ws + 4352);  // 1 MB
  float* eT = (float*)(ws + 1052928);                 // 1 MB
  float* pm1 = (float*)(ws + 2101504);
  float* pm2 = (float*)(ws + 2232576);
  int* pk = (int*)(ws + 2363648);
  int* idx_buf = (int*)(ws + 2494720);
  int* rlist = (int*)(ws + 2625792);

  initK<<<1, 1, 0, stream>>>(loss_sum, rcount);
  enormK<<<4, 256, 0, stream>>>(emb, enorm);
  transK<<<dim3(32, 8), 256, 0, stream>>>(emb, eT);
  prepBK<<<64, 256, 0, stream>>>(emb, bp);
  distK<<<512, 256, 0, stream>>>(z, bp, enorm, pm1, pm2, pk);
  finishK<<<128, 256, 0, stream>>>(pm1, pm2, pk, idx_buf, out, rlist, rcount);
  refineK<<<256, 256, 0, stream>>>(z, eT, enorm, rlist, rcount, idx_buf, out);
  outputK<<<2048, 256, 0, stream>>>(z, emb, idx_buf, out, loss_sum);
  finalK<<<1, 1, 0, stream>>>(loss_sum, out);
}

// Round 13
// 238.920 us; speedup vs baseline: 1.3751x; 1.0423x over previous
//
#include <hip/hip_runtime.h>

// VectorQuantizer: z (32,256,32,32) f32, embedding (1024,256) f32.
// N=32768 rows (n = b*1024 + h*32 + w), D=256, K=1024.
// Out (f32, concat): z_q_st [8388608] (B,C,H,W), vq_loss [1], idx [32768].
// z_flat[n][c] = z[b*262144 + c*1024 + (n & 1023)]
//
// v9 = v8 with refineK rebuilt wave-per-row (v8 spilled: VGPR=256, 90MB
// scratch writes). Lane owns 16 codes -> 16 indep FMA chains per coalesced
// eT load; depth-4 static double-buffer; no __syncthreads (per-wave LDS
// slice). Chain = ascending-d __fmaf_rn -> bit-identical to proven refine.
// distK (MFMA 2-limb bf16), prepBK, enormK, transK, finishK, outputK same.
// ws: [0] loss f64; [16) rcount; [64) enorm 4KB; [4352) bp 1MB;
//     [1052928) eT 1MB; [2101504) pm1; [2232576) pm2; [2363648) pk;
//     [2494720) idx_buf; [2625792) rlist.

#define TAU 4.0e-4f

typedef __attribute__((ext_vector_type(8))) short short8b;   // 8 bf16
typedef __attribute__((ext_vector_type(4))) float f32x4;

__device__ __forceinline__ unsigned short f2bf_rne(float x) {
  unsigned int u = __float_as_uint(x);
  unsigned int r = u + 0x7fffu + ((u >> 16) & 1u);
  return (unsigned short)(r >> 16);
}
__device__ __forceinline__ float bf2f(unsigned short s) {
  return __uint_as_float(((unsigned int)s) << 16);
}

__device__ __forceinline__ float np_pairwise256_sq(const float* a) {
  float tot = 0.0f;
#pragma unroll
  for (int blk = 0; blk < 2; ++blk) {
    const float* p = a + blk * 128;
    float r[8];
#pragma unroll
    for (int j = 0; j < 8; ++j) r[j] = __fmul_rn(p[j], p[j]);
    for (int i = 8; i < 128; i += 8) {
#pragma unroll
      for (int j = 0; j < 8; ++j) r[j] = __fadd_rn(r[j], __fmul_rn(p[i + j], p[i + j]));
    }
    float res = __fadd_rn(__fadd_rn(__fadd_rn(r[0], r[1]), __fadd_rn(r[2], r[3])),
                          __fadd_rn(__fadd_rn(r[4], r[5]), __fadd_rn(r[6], r[7])));
    tot = (blk == 0) ? res : __fadd_rn(tot, res);
  }
  return tot;
}

__global__ void initK(double* loss_sum, int* rcount) {
  *loss_sum = 0.0;
  *rcount = 0;
}

__global__ __launch_bounds__(256) void enormK(const float* __restrict__ emb,
                                              float* __restrict__ enorm) {
  const int k = blockIdx.x * 256 + threadIdx.x;
  enorm[k] = np_pairwise256_sq(emb + (size_t)k * 256);
}

// eT[d][k] = emb[k][d], 32x32 LDS-tiled transpose.
__global__ __launch_bounds__(256) void transK(const float* __restrict__ emb,
                                              float* __restrict__ eT) {
  __shared__ float t[32][33];
  const int k0 = blockIdx.x * 32, d0 = blockIdx.y * 32;
  const int lx = threadIdx.x & 31, ly = threadIdx.x >> 5;
#pragma unroll
  for (int r = 0; r < 4; ++r)
    t[ly + r * 8][lx] = emb[(size_t)(k0 + ly + r * 8) * 256 + d0 + lx];
  __syncthreads();
#pragma unroll
  for (int r = 0; r < 4; ++r)
    eT[(size_t)(d0 + ly + r * 8) * 1024 + k0 + lx] = t[lx][ly + r * 8];
}

// B_pack: slot ushort-index = ((C*16 + limb*8 + kb)*64 + lane)*8.
__global__ __launch_bounds__(256) void prepBK(const float* __restrict__ emb,
                                              unsigned short* __restrict__ bp) {
  const int C = blockIdx.x;  // 64 code-blocks of 16
  const int t = threadIdx.x;
  const int n = t & 15, kb = (t >> 4) & 7, limb = t >> 7;
  const float* er = emb + (size_t)(C * 16 + n) * 256 + kb * 32;
#pragma unroll
  for (int s = 0; s < 4; ++s) {
    unsigned int w[4];
#pragma unroll
    for (int p = 0; p < 4; ++p) {
      unsigned short v2[2];
#pragma unroll
      for (int q = 0; q < 2; ++q) {
        float x = er[s * 8 + p * 2 + q];
        unsigned short hi = f2bf_rne(x);
        v2[q] = (limb == 0) ? hi : f2bf_rne(x - bf2f(hi));
      }
      w[p] = (unsigned int)v2[0] | ((unsigned int)v2[1] << 16);
    }
    size_t idx = ((size_t)(C * 16 + limb * 8 + kb) * 64 + (n + 16 * s)) * 8;
    *(uint4*)(bp + idx) = make_uint4(w[0], w[1], w[2], w[3]);
  }
}

// MFMA distance pass: wave = 16 rows x 1024 codes, (min1,min2,idx) -> ws.
__global__ __launch_bounds__(256) void distK(const float* __restrict__ z,
                                             const unsigned short* __restrict__ bp,
                                             const float* __restrict__ enorm,
                                             float* __restrict__ pm1,
                                             float* __restrict__ pm2,
                                             int* __restrict__ pk) {
  const int tid = threadIdx.x;
  const int wid = tid >> 6, lane = tid & 63;
  const int R = blockIdx.x * 4 + wid;  // 2048 row-blocks of 16
  const int n0w = R * 16;
  const int b = n0w >> 10, hw0 = n0w & 1023;
  const int s = lane >> 4, m = lane & 15;
  const float* zb = z + (size_t)b * 262144 + hw0 + m;

  short8b az[8], al[8];
#pragma unroll
  for (int kb = 0; kb < 8; ++kb) {
    float f[8];
#pragma unroll
    for (int i = 0; i < 8; ++i)
      f[i] = zb[(size_t)(kb * 32 + s * 8 + i) * 1024];
#pragma unroll
    for (int i = 0; i < 8; ++i) {
      unsigned short hi = f2bf_rne(f[i]);
      az[kb][i] = (short)hi;
      al[kb][i] = (short)f2bf_rne(f[i] - bf2f(hi));
    }
  }

  float m1[4], m2[4];
  int k1i[4];
#pragma unroll
  for (int r = 0; r < 4; ++r) { m1[r] = 3.0e38f; m2[r] = 3.0e38f; k1i[r] = 0; }

  short8b be[8], bl[8];
#pragma unroll
  for (int kb = 0; kb < 8; ++kb)
    be[kb] = *(const short8b*)(bp + ((size_t)kb * 64 + lane) * 8);

  for (int nt = 0; nt < 64; ++nt) {
    f32x4 acc = {0.0f, 0.0f, 0.0f, 0.0f};
    float en = enorm[nt * 16 + m];
#pragma unroll
    for (int kb = 0; kb < 8; ++kb)
      acc = __builtin_amdgcn_mfma_f32_16x16x32_bf16(az[kb], be[kb], acc, 0, 0, 0);
#pragma unroll
    for (int kb = 0; kb < 8; ++kb)
      bl[kb] = *(const short8b*)(bp + ((size_t)(nt * 16 + 8 + kb) * 64 + lane) * 8);
#pragma unroll
    for (int kb = 0; kb < 8; ++kb)
      acc = __builtin_amdgcn_mfma_f32_16x16x32_bf16(al[kb], be[kb], acc, 0, 0, 0);
    if (nt < 63) {
#pragma unroll
      for (int kb = 0; kb < 8; ++kb)
        be[kb] = *(const short8b*)(bp + ((size_t)((nt + 1) * 16 + kb) * 64 + lane) * 8);
    }
#pragma unroll
    for (int kb = 0; kb < 8; ++kb)
      acc = __builtin_amdgcn_mfma_f32_16x16x32_bf16(az[kb], bl[kb], acc, 0, 0, 0);
    const int code = nt * 16 + m;
#pragma unroll
    for (int r = 0; r < 4; ++r) {
      float v = en - 2.0f * acc[r];
      if (v < m1[r]) { m2[r] = m1[r]; m1[r] = v; k1i[r] = code; }
      else if (v < m2[r]) { m2[r] = v; }
    }
  }

#pragma unroll
  for (int r = 0; r < 4; ++r) {
    float a1 = m1[r], a2 = m2[r];
    int ai = k1i[r];
#pragma unroll
    for (int mask = 1; mask < 16; mask <<= 1) {
      float b1 = __shfl_xor(a1, mask);
      float b2 = __shfl_xor(a2, mask);
      int bi = __shfl_xor(ai, mask);
      if (b1 < a1 || (b1 == a1 && bi < ai)) { a2 = fminf(a1, b2); a1 = b1; ai = bi; }
      else { a2 = fminf(a2, b1); }
    }
    if (m == 0) {
      int n = n0w + s * 4 + r;
      pm1[n] = a1;
      pm2[n] = a2;
      pk[n] = ai;
    }
  }
}

// Flat merge + prelim idx writes + compact flagged rows.
__global__ __launch_bounds__(256) void finishK(const float* __restrict__ pm1,
                                               const float* __restrict__ pm2,
                                               const int* __restrict__ pk,
                                               int* __restrict__ idx_buf,
                                               float* __restrict__ out,
                                               int* __restrict__ rlist,
                                               int* __restrict__ rcount) {
  const int n = blockIdx.x * 256 + threadIdx.x;  // 128 blocks
  float a1 = pm1[n], a2 = pm2[n];
  int ai = pk[n];
  idx_buf[n] = ai;
  out[(size_t)8388609 + n] = (float)ai;
  if (a2 - a1 < TAU) {
    int p = atomicAdd(rcount, 1);
    rlist[p] = n;
  }
}

// np-f32 bit-exact re-derivation: ONE WAVE PER ROW. Lane owns codes
// lane*16..lane*16+15 (16 indep FMA chains / load). Depth-4 static dbuf.
__global__ __launch_bounds__(256) void refineK(const float* __restrict__ z,
                                               const float* __restrict__ eT,
                                               const float* __restrict__ enorm,
                                               const int* __restrict__ rlist,
                                               const int* __restrict__ rcount,
                                               int* __restrict__ idx_buf,
                                               float* __restrict__ out) {
  __shared__ float zr[4][256];  // per-wave private slice; no barriers needed
  const int tid = threadIdx.x;
  const int wid = tid >> 6, lane = tid & 63;
  const int cnt = *rcount;
  float* zw = zr[wid];
  for (int base = blockIdx.x * 4; base < cnt; base += gridDim.x * 4) {
    const int ii = base + wid;
    if (ii >= cnt) continue;
    const int n = rlist[ii];
    const int bb = n >> 10, hw = n & 1023;
#pragma unroll
    for (int s = 0; s < 4; ++s)
      zw[lane + s * 64] = z[(size_t)bb * 262144 + (size_t)(lane + s * 64) * 1024 + hw];
    const float a32 = np_pairwise256_sq(zw);

    float bch[16];
#pragma unroll
    for (int j = 0; j < 16; ++j) bch[j] = 0.0f;
    const float* eb = eT + lane * 16;

    float4 B0[4], B1[4], B2[4], B3[4];
#pragma unroll
    for (int q = 0; q < 4; ++q) {
      B0[q] = *(const float4*)(eb + (size_t)0 * 1024 + q * 4);
      B1[q] = *(const float4*)(eb + (size_t)1 * 1024 + q * 4);
      B2[q] = *(const float4*)(eb + (size_t)2 * 1024 + q * 4);
      B3[q] = *(const float4*)(eb + (size_t)3 * 1024 + q * 4);
    }
#pragma unroll 1
    for (int d = 0; d < 256; d += 4) {
      const bool more = (d + 4) < 256;
      {
        float zv = zw[d];
#pragma unroll
        for (int q = 0; q < 4; ++q) {
          bch[q * 4 + 0] = __fmaf_rn(zv, B0[q].x, bch[q * 4 + 0]);
          bch[q * 4 + 1] = __fmaf_rn(zv, B0[q].y, bch[q * 4 + 1]);
          bch[q * 4 + 2] = __fmaf_rn(zv, B0[q].z, bch[q * 4 + 2]);
          bch[q * 4 + 3] = __fmaf_rn(zv, B0[q].w, bch[q * 4 + 3]);
        }
        if (more) {
#pragma unroll
          for (int q = 0; q < 4; ++q)
            B0[q] = *(const float4*)(eb + (size_t)(d + 4) * 1024 + q * 4);
        }
      }
      {
        float zv = zw[d + 1];
#pragma unroll
        for (int q = 0; q < 4; ++q) {
          bch[q * 4 + 0] = __fmaf_rn(zv, B1[q].x, bch[q * 4 + 0]);
          bch[q * 4 + 1] = __fmaf_rn(zv, B1[q].y, bch[q * 4 + 1]);
          bch[q * 4 + 2] = __fmaf_rn(zv, B1[q].z, bch[q * 4 + 2]);
          bch[q * 4 + 3] = __fmaf_rn(zv, B1[q].w, bch[q * 4 + 3]);
        }
        if (more) {
#pragma unroll
          for (int q = 0; q < 4; ++q)
            B1[q] = *(const float4*)(eb + (size_t)(d + 5) * 1024 + q * 4);
        }
      }
      {
        float zv = zw[d + 2];
#pragma unroll
        for (int q = 0; q < 4; ++q) {
          bch[q * 4 + 0] = __fmaf_rn(zv, B2[q].x, bch[q * 4 + 0]);
          bch[q * 4 + 1] = __fmaf_rn(zv, B2[q].y, bch[q * 4 + 1]);
          bch[q * 4 + 2] = __fmaf_rn(zv, B2[q].z, bch[q * 4 + 2]);
          bch[q * 4 + 3] = __fmaf_rn(zv, B2[q].w, bch[q * 4 + 3]);
        }
        if (more) {
#pragma unroll
          for (int q = 0; q < 4; ++q)
            B2[q] = *(const float4*)(eb + (size_t)(d + 6) * 1024 + q * 4);
        }
      }
      {
        float zv = zw[d + 3];
#pragma unroll
        for (int q = 0; q < 4; ++q) {
          bch[q * 4 + 0] = __fmaf_rn(zv, B3[q].x, bch[q * 4 + 0]);
          bch[q * 4 + 1] = __fmaf_rn(zv, B3[q].y, bch[q * 4 + 1]);
          bch[q * 4 + 2] = __fmaf_rn(zv, B3[q].z, bch[q * 4 + 2]);
          bch[q * 4 + 3] = __fmaf_rn(zv, B3[q].w, bch[q * 4 + 3]);
        }
        if (more) {
#pragma unroll
          for (int q = 0; q < 4; ++q)
            B3[q] = *(const float4*)(eb + (size_t)(d + 7) * 1024 + q * 4);
        }
      }
    }

    // d32 = fl(fl(a32 - 2b) + c); per-lane ascending j keeps first index
    float best = 3.0e38f;
    int bi = 1 << 30;
#pragma unroll
    for (int j = 0; j < 16; ++j) {
      const int k = lane * 16 + j;
      float tb = __fmul_rn(2.0f, bch[j]);
      float d32 = __fadd_rn(__fsub_rn(a32, tb), enorm[k]);
      if (d32 < best) { best = d32; bi = k; }
    }
#pragma unroll
    for (int mask = 1; mask < 64; mask <<= 1) {
      float ov = __shfl_xor(best, mask);
      int oi = __shfl_xor(bi, mask);
      if (ov < best || (ov == best && oi < bi)) { best = ov; bi = oi; }
    }
    if (lane == 0) {
      idx_buf[n] = bi;
      out[(size_t)8388609 + n] = (float)bi;
    }
  }
}

// z_q gather + z_q_st write + loss. Block = 64 rows x 64-channel quarter.
__global__ __launch_bounds__(256) void outputK(const float* __restrict__ z,
                                               const float* __restrict__ emb,
                                               const int* __restrict__ idx_buf,
                                               float* __restrict__ out,
                                               double* __restrict__ loss_sum) {
  __shared__ float el[64 * 65];  // stride-65 pad -> conflict-free
  __shared__ int sidx[64];
  __shared__ double sloss[4];

  const int tid = threadIdx.x;
  const int rg = blockIdx.x >> 2;
  const int q = blockIdx.x & 3;       // channel quarter
  const int n0 = rg * 64;
  const int b = n0 >> 10;
  const int hw0 = n0 & 1023;

  if (tid < 64) sidx[tid] = idx_buf[n0 + tid];
  __syncthreads();

#pragma unroll
  for (int rep = 0; rep < 16; ++rep) {
    int idx = rep * 256 + tid;
    int r = idx >> 6, i = idx & 63;
    el[r * 65 + i] = emb[(size_t)sidx[r] * 256 + q * 64 + i];
  }
  __syncthreads();

  const int m = tid & 63;
  const int cq = tid >> 6;
  const size_t zb = (size_t)b * 262144 + hw0 + m;
  double acc = 0.0;
#pragma unroll
  for (int it = 0; it < 16; ++it) {
    int cl = it * 4 + cq;             // local channel 0..63
    int c = q * 64 + cl;
    float zv = z[zb + (size_t)c * 1024];
    float zq = el[m * 65 + cl];
    float d = zq - zv;
    out[zb + (size_t)c * 1024] = zv + d;  // z + (z_q - z), f32
    acc += (double)(d * d);
  }
  for (int mask = 1; mask < 64; mask <<= 1) acc += __shfl_xor(acc, mask);
  if ((tid & 63) == 0) sloss[tid >> 6] = acc;
  __syncthreads();
  if (tid == 0)
    atomicAdd(loss_sum, sloss[0] + sloss[1] + sloss[2] + sloss[3]);
}

__global__ void finalK(const double* loss_sum, float* out) {
  double s = *loss_sum;
  out[8388608] = (float)(1.25 * s / 8388608.0);  // (1+beta)*mean, beta=0.25
}

extern "C" void kernel_launch(void* const* d_in, const int* in_sizes, int n_in,
                              void* d_out, int out_size, void* d_ws, size_t ws_size,
                              hipStream_t stream) {
  const float* z = (const float*)d_in[0];
  const float* emb = (const float*)d_in[1];
  float* out = (float*)d_out;
  char* ws = (char*)d_ws;
  double* loss_sum = (double*)ws;
  int* rcount = (int*)(ws + 16);
  float* enorm = (float*)(ws + 64);
  unsigned short* bp = (unsigned short*)(ws + 4352);  // 1 MB
  float* eT = (float*)(ws + 1052928);                 // 1 MB
  float* pm1 = (float*)(ws + 2101504);
  float* pm2 = (float*)(ws + 2232576);
  int* pk = (int*)(ws + 2363648);
  int* idx_buf = (int*)(ws + 2494720);
  int* rlist = (int*)(ws + 2625792);

  initK<<<1, 1, 0, stream>>>(loss_sum, rcount);
  enormK<<<4, 256, 0, stream>>>(emb, enorm);
  transK<<<dim3(32, 8), 256, 0, stream>>>(emb, eT);
  prepBK<<<64, 256, 0, stream>>>(emb, bp);
  distK<<<512, 256, 0, stream>>>(z, bp, enorm, pm1, pm2, pk);
  finishK<<<128, 256, 0, stream>>>(pm1, pm2, pk, idx_buf, out, rlist, rcount);
  refineK<<<512, 256, 0, stream>>>(z, eT, enorm, rlist, rcount, idx_buf, out);
  outputK<<<2048, 256, 0, stream>>>(z, emb, idx_buf, out, loss_sum);
  finalK<<<1, 1, 0, stream>>>(loss_sum, out);
}